// Round 1
// baseline (202.103 us; speedup 1.0000x reference)
//
#include <hip/hip_runtime.h>

// Problem constants: C=32 states, L=4 fanout, M=128 symbols, DEPTH=7
// level starts: {0,1,5,21,85,341,1365,5461,21845}, 64 subtrees rooted at level 3.

static constexpr int OFF_ASP    = 0;                      // A_SP  [i*128 + j*4 + l]   (4096)
static constexpr int OFF_LG     = 4096;                   // log smA + log smSP, same layout
static constexpr int OFF_SMBT   = 8192;                   // smB transposed  [m*32+i]  (4096)
static constexpr int OFF_LOGBT  = 12288;                  // log smB transposed        (4096)
static constexpr int OFF_SMPIT  = 16384;                  // smPi transposed [l*32+i]  (128)
static constexpr int OFF_LOGPIT = 16512;                  // log smPi transposed       (128)
static constexpr int OFF_BETA   = 16640;                  // beta   [node*32+i], 21845*32
static constexpr int OFF_TBETA  = OFF_BETA + 21845 * 32;  // t_beta [node*32+i], 5461*32
static constexpr int OFF_EPS3   = OFF_TBETA + 5461 * 32;  // level-3 eps handoff, 64*32
static constexpr int OFF_ACC    = OFF_EPS3 + 2048;        // fp64 accumulator (8B, 8-aligned)

__device__ __forceinline__ float rsum32(float v) {
  v += __shfl_xor(v, 1);
  v += __shfl_xor(v, 2);
  v += __shfl_xor(v, 4);
  v += __shfl_xor(v, 8);
  v += __shfl_xor(v, 16);
  return v;
}

// ---------------- K1: softmaxes + logs + zero accumulator ----------------
__global__ __launch_bounds__(128) void k_prep(const float* __restrict__ A,
                                              const float* __restrict__ B,
                                              const float* __restrict__ Pi,
                                              const float* __restrict__ SP,
                                              float* __restrict__ ws) {
  __shared__ float sSP[4], sLSP[4];
  const int t = threadIdx.x;
  if (t == 0) {
    float m = SP[0];
    for (int l = 1; l < 4; ++l) m = fmaxf(m, SP[l]);
    float e[4], s = 0.f;
    for (int l = 0; l < 4; ++l) { e[l] = expf(SP[l] - m); s += e[l]; }
    float ls = logf(s);
    for (int l = 0; l < 4; ++l) { sSP[l] = e[l] / s; sLSP[l] = (SP[l] - m) - ls; }
    *(double*)(ws + OFF_ACC) = 0.0;
  }
  __syncthreads();
  // softmax over axis 0 of A per (j,l) column; A_SP = smA * smSP[l], LG = log smA + log smSP[l]
  {
    const int jl = t;           // 0..127
    const int l = jl & 3;
    float m = -3.0e38f;
    for (int i = 0; i < 32; ++i) m = fmaxf(m, A[i * 128 + jl]);
    float s = 0.f;
    for (int i = 0; i < 32; ++i) s += expf(A[i * 128 + jl] - m);
    float ls = logf(s);
    for (int i = 0; i < 32; ++i) {
      float x = A[i * 128 + jl] - m;
      float sm = expf(x) / s;
      ws[OFF_ASP + i * 128 + jl] = sm * sSP[l];
      ws[OFF_LG + i * 128 + jl] = (x - ls) + sLSP[l];
    }
  }
  // softmax over axis 1 of B per row i; stored TRANSPOSED [m*32+i]
  if (t < 32) {
    const int i = t;
    float m = -3.0e38f;
    for (int q = 0; q < 128; ++q) m = fmaxf(m, B[i * 128 + q]);
    float s = 0.f;
    for (int q = 0; q < 128; ++q) s += expf(B[i * 128 + q] - m);
    float ls = logf(s);
    for (int q = 0; q < 128; ++q) {
      float x = B[i * 128 + q] - m;
      ws[OFF_SMBT + q * 32 + i] = expf(x) / s;
      ws[OFF_LOGBT + q * 32 + i] = x - ls;
    }
  }
  // softmax over axis 0 of Pi per column l; stored TRANSPOSED [l*32+i]
  if (t < 4) {
    const int l = t;
    float m = -3.0e38f;
    for (int i = 0; i < 32; ++i) m = fmaxf(m, Pi[i * 4 + l]);
    float s = 0.f;
    for (int i = 0; i < 32; ++i) s += expf(Pi[i * 4 + l] - m);
    float ls = logf(s);
    for (int i = 0; i < 32; ++i) {
      float x = Pi[i * 4 + l] - m;
      ws[OFF_SMPIT + l * 32 + i] = expf(x) / s;
      ws[OFF_LOGPIT + l * 32 + i] = x - ls;
    }
  }
}

// ---------------- K2: per-subtree upward sweep, levels 7 -> 3 ----------------
// 64 blocks, 256 threads = 8 groups of 32 lanes; lane = hidden state.
__global__ __launch_bounds__(256) void k_up_sub(const int* __restrict__ labels,
                                                float* __restrict__ ws) {
  __shared__ float sA[4096];   // A_SP as [(j*4+l)*32 + i]  (lane-i conflict-free)
  __shared__ float sBt[4096];  // smB  [m*32 + i]
  __shared__ float sPt[128];   // smPi [l*32 + i]
  __shared__ float bufB[2048]; // 64-node beta buffer
  __shared__ float bufA[512];  // 16-node beta buffer
  const int t = threadIdx.x, blk = blockIdx.x;
  const int lane = t & 31, grp = t >> 5;
  const float* ASP = ws + OFF_ASP;
  float* beta = ws + OFF_BETA;
  float* tbet = ws + OFF_TBETA;
  for (int idx = t; idx < 4096; idx += 256) {
    int i = idx >> 7, jl = idx & 127;
    sA[jl * 32 + i] = ASP[idx];
  }
  for (int idx = t; idx < 4096; idx += 256) sBt[idx] = ws[OFF_SMBT + idx];
  if (t < 128) sPt[t] = ws[OFF_SMPIT + t];
  __syncthreads();

  // level-6 parents (64 per subtree), leaf betas computed inline in registers
  {
    const int pg = 1365 + blk * 64;   // level-6 global base
    const int lg = 5461 + blk * 256;  // leaf global base
    for (int p = grp; p < 64; p += 8) {
      float blv[4];
      const int gleaf = lg + p * 4;
#pragma unroll
      for (int l = 0; l < 4; ++l) {
        int lab = labels[gleaf + l];
        // leaf_pos = (leaf local index) % 4 = l
        float v = sPt[l * 32 + lane] * sBt[lab * 32 + lane];
        float s = rsum32(v);
        v /= s;
        blv[l] = v;
        beta[(gleaf + l) * 32 + lane] = v;
      }
      float tb = 0.f;
#pragma unroll
      for (int l = 0; l < 4; ++l) {
#pragma unroll 8
        for (int j = 0; j < 32; ++j) {
          float bj = __shfl(blv[l], j, 32);
          tb = fmaf(sA[(j * 4 + l) * 32 + lane], bj, tb);
        }
      }
      const int gn = pg + p;
      const int lab = labels[gn];
      float bl = tb * sBt[lab * 32 + lane];
      float s = rsum32(bl);
      bl /= s;
      tbet[gn * 32 + lane] = tb;
      beta[gn * 32 + lane] = bl;
      bufB[p * 32 + lane] = bl;
    }
  }
  __syncthreads();

  // levels 5, 4, 3 (children staged in LDS, ping-pong)
  float* chb = bufB;
  float* prb = bufA;
  for (int ld = 0; ld < 3; ++ld) {
    const int np = (ld == 0) ? 16 : (ld == 1) ? 4 : 1;
    const int ps = (ld == 0) ? (341 + blk * 16) : (ld == 1) ? (85 + blk * 4) : (21 + blk);
    for (int p = grp; p < np; p += 8) {
      const float* ch = chb + p * 128;
      float tb = 0.f;
#pragma unroll
      for (int l = 0; l < 4; ++l) {
#pragma unroll 8
        for (int j = 0; j < 32; ++j)
          tb = fmaf(sA[(j * 4 + l) * 32 + lane], ch[l * 32 + j], tb);
      }
      const int gn = ps + p;
      const int lab = labels[gn];
      float bl = tb * sBt[lab * 32 + lane];
      float s = rsum32(bl);
      bl /= s;
      tbet[gn * 32 + lane] = tb;
      beta[gn * 32 + lane] = bl;
      prb[p * 32 + lane] = bl;
    }
    __syncthreads();
    float* tmp = chb; chb = prb; prb = tmp;
  }
}

// ---------------- K3: upward sweep, levels 2 -> 0 (one block) ----------------
__global__ __launch_bounds__(256) void k_up_top(const int* __restrict__ labels,
                                                float* __restrict__ ws) {
  __shared__ float sA[4096];
  __shared__ float sBt[4096];
  __shared__ float bufA[2048];  // level-3 children (64 nodes)
  __shared__ float bufB[512];
  const int t = threadIdx.x, lane = t & 31, grp = t >> 5;
  const float* ASP = ws + OFF_ASP;
  float* beta = ws + OFF_BETA;
  float* tbet = ws + OFF_TBETA;
  for (int idx = t; idx < 4096; idx += 256) {
    int i = idx >> 7, jl = idx & 127;
    sA[jl * 32 + i] = ASP[idx];
  }
  for (int idx = t; idx < 4096; idx += 256) sBt[idx] = ws[OFF_SMBT + idx];
  for (int idx = t; idx < 2048; idx += 256) bufA[idx] = beta[21 * 32 + idx];
  __syncthreads();
  float* chb = bufA;
  float* prb = bufB;
  for (int ld = 0; ld < 3; ++ld) {
    const int np = (ld == 0) ? 16 : (ld == 1) ? 4 : 1;
    const int ps = (ld == 0) ? 5 : (ld == 1) ? 1 : 0;
    for (int p = grp; p < np; p += 8) {
      const float* ch = chb + p * 128;
      float tb = 0.f;
#pragma unroll
      for (int l = 0; l < 4; ++l) {
#pragma unroll 8
        for (int j = 0; j < 32; ++j)
          tb = fmaf(sA[(j * 4 + l) * 32 + lane], ch[l * 32 + j], tb);
      }
      const int gn = ps + p;
      const int lab = labels[gn];
      float bl = tb * sBt[lab * 32 + lane];
      float s = rsum32(bl);
      bl /= s;
      tbet[gn * 32 + lane] = tb;
      beta[gn * 32 + lane] = bl;
      prb[p * 32 + lane] = bl;
    }
    __syncthreads();
    float* tmp = chb; chb = prb; prb = tmp;
  }
}

// ---------------- K4: downward sweep, levels 0 -> 3 (one block) ----------------
// te[p,i,j,l] = beta_ch[l,j]*A_SP[i,j,l]*r[i], r = eps/tb. Factor through
// w[j,l] = sum_i A_SP*r and u[j,l] = sum_i A_SP*r*LG: eps_ch = bc*w, ll += bc*u.
__global__ __launch_bounds__(256) void k_down_top(const int* __restrict__ labels,
                                                  float* __restrict__ ws) {
  __shared__ float sA2[4096];  // A_SP as [l*1024 + i*32 + j]  (lane-j conflict-free)
  __shared__ float sLG[4096];  // LG   same layout
  __shared__ float sLBt[4096]; // log smB [m*32 + i]
  __shared__ float epsT[85 * 32];
  const int t = threadIdx.x, lane = t & 31, grp = t >> 5;
  const float* ASP = ws + OFF_ASP;
  const float* LGg = ws + OFF_LG;
  const float* beta = ws + OFF_BETA;
  const float* tbet = ws + OFF_TBETA;
  for (int idx = t; idx < 4096; idx += 256) {
    int i = idx >> 7, j = (idx >> 2) & 31, l = idx & 3;
    sA2[l * 1024 + i * 32 + j] = ASP[idx];
    sLG[l * 1024 + i * 32 + j] = LGg[idx];
  }
  for (int idx = t; idx < 4096; idx += 256) sLBt[idx] = ws[OFF_LOGBT + idx];
  if (t < 32) epsT[t] = beta[t];  // eps[0] = beta[0]
  __syncthreads();
  double ll = 0.0;
  if (grp == 0) {  // root's eps*logB term
    int lab0 = labels[0];
    ll += (double)(epsT[lane] * sLBt[lab0 * 32 + lane]);
  }
  for (int d = 0; d < 3; ++d) {
    const int np = (d == 0) ? 1 : (d == 1) ? 4 : 16;
    const int ps = (d == 0) ? 0 : (d == 1) ? 1 : 5;
    const int cs = (d == 0) ? 1 : (d == 1) ? 5 : 21;
    for (int p = grp; p < np; p += 8) {
      const int pn = ps + p;
      float r = epsT[pn * 32 + lane] / tbet[pn * 32 + lane];
      float bc[4];
      int labc[4];
#pragma unroll
      for (int l = 0; l < 4; ++l) {
        bc[l] = beta[(cs + p * 4 + l) * 32 + lane];
        labc[l] = labels[cs + p * 4 + l];
      }
#pragma unroll
      for (int l = 0; l < 4; ++l) {
        float wl = 0.f, ul = 0.f;
#pragma unroll 8
        for (int i = 0; i < 32; ++i) {
          float ri = __shfl(r, i, 32);
          float a = sA2[l * 1024 + i * 32 + lane] * ri;
          wl += a;
          ul = fmaf(a, sLG[l * 1024 + i * 32 + lane], ul);
        }
        float e = bc[l] * wl;
        epsT[(cs + p * 4 + l) * 32 + lane] = e;
        ll += (double)(bc[l] * ul);                      // t_eps * (logA + logSP)
        ll += (double)(e * sLBt[labc[l] * 32 + lane]);   // eps * logB
      }
    }
    __syncthreads();
  }
  // hand off level-3 eps (nodes 21..84)
  for (int idx = t; idx < 2048; idx += 256) ws[OFF_EPS3 + idx] = epsT[21 * 32 + idx];
#pragma unroll
  for (int k = 32; k >= 1; k >>= 1) ll += __shfl_xor(ll, k);
  if ((t & 63) == 0) atomicAdd((double*)(ws + OFF_ACC), ll);
}

// ---------------- K5: per-subtree downward sweep, levels 3 -> 6 ----------------
__global__ __launch_bounds__(256) void k_down_sub(const int* __restrict__ labels,
                                                  float* __restrict__ ws) {
  __shared__ float sA2[4096];
  __shared__ float sLG[4096];
  __shared__ float sLBt[4096];
  __shared__ float sLPt[128];
  __shared__ float leps[85 * 32];  // local eps: root=0, L4=1..4, L5=5..20, L6=21..84
  const int t = threadIdx.x, blk = blockIdx.x, lane = t & 31, grp = t >> 5;
  const float* ASP = ws + OFF_ASP;
  const float* LGg = ws + OFF_LG;
  const float* beta = ws + OFF_BETA;
  const float* tbet = ws + OFF_TBETA;
  for (int idx = t; idx < 4096; idx += 256) {
    int i = idx >> 7, j = (idx >> 2) & 31, l = idx & 3;
    sA2[l * 1024 + i * 32 + j] = ASP[idx];
    sLG[l * 1024 + i * 32 + j] = LGg[idx];
  }
  for (int idx = t; idx < 4096; idx += 256) sLBt[idx] = ws[OFF_LOGBT + idx];
  if (t < 128) sLPt[t] = ws[OFF_LOGPIT + t];
  if (t < 32) leps[t] = ws[OFF_EPS3 + blk * 32 + t];
  __syncthreads();
  double ll = 0.0;
  for (int d = 0; d < 4; ++d) {  // ref levels 3..6
    const int np = (d == 0) ? 1 : (d == 1) ? 4 : (d == 2) ? 16 : 64;
    const int pb = (d == 0) ? 0 : (d == 1) ? 1 : (d == 2) ? 5 : 21;
    const int cb = (d == 0) ? 1 : (d == 1) ? 5 : (d == 2) ? 21 : 85;
    const int gp = (d == 0) ? (21 + blk) : (d == 1) ? (85 + blk * 4)
                 : (d == 2) ? (341 + blk * 16) : (1365 + blk * 64);
    const int gc = (d == 0) ? (85 + blk * 4) : (d == 1) ? (341 + blk * 16)
                 : (d == 2) ? (1365 + blk * 64) : (5461 + blk * 256);
    for (int p = grp; p < np; p += 8) {
      const int lp = pb + p;
      float r = leps[lp * 32 + lane] / tbet[(gp + p) * 32 + lane];
      float bc[4];
      int labc[4];
#pragma unroll
      for (int l = 0; l < 4; ++l) {
        bc[l] = beta[(gc + p * 4 + l) * 32 + lane];
        labc[l] = labels[gc + p * 4 + l];
      }
#pragma unroll
      for (int l = 0; l < 4; ++l) {
        float wl = 0.f, ul = 0.f;
#pragma unroll 8
        for (int i = 0; i < 32; ++i) {
          float ri = __shfl(r, i, 32);
          float a = sA2[l * 1024 + i * 32 + lane] * ri;
          wl += a;
          ul = fmaf(a, sLG[l * 1024 + i * 32 + lane], ul);
        }
        float e = bc[l] * wl;
        ll += (double)(bc[l] * ul);                     // t_eps * (logA + logSP)
        ll += (double)(e * sLBt[labc[l] * 32 + lane]);  // eps * logB
        if (d < 3) {
          leps[(cb + p * 4 + l) * 32 + lane] = e;
        } else {
          // leaf: pos = l exactly; eps * logPi
          ll += (double)(e * sLPt[l * 32 + lane]);
        }
      }
    }
    __syncthreads();
  }
#pragma unroll
  for (int k = 32; k >= 1; k >>= 1) ll += __shfl_xor(ll, k);
  if ((t & 63) == 0) atomicAdd((double*)(ws + OFF_ACC), ll);
}

// ---------------- K6: write scalar output ----------------
__global__ void k_final(const float* __restrict__ ws, float* __restrict__ out) {
  if (threadIdx.x == 0 && blockIdx.x == 0)
    out[0] = (float)(*(const double*)(ws + OFF_ACC));
}

extern "C" void kernel_launch(void* const* d_in, const int* in_sizes, int n_in,
                              void* d_out, int out_size, void* d_ws, size_t ws_size,
                              hipStream_t stream) {
  (void)in_sizes; (void)n_in; (void)out_size; (void)ws_size;
  const int* labels = (const int*)d_in[0];
  const float* A = (const float*)d_in[1];
  const float* B = (const float*)d_in[2];
  const float* Pi = (const float*)d_in[3];
  const float* SP = (const float*)d_in[4];
  float* ws = (float*)d_ws;
  float* out = (float*)d_out;

  hipLaunchKernelGGL(k_prep, dim3(1), dim3(128), 0, stream, A, B, Pi, SP, ws);
  hipLaunchKernelGGL(k_up_sub, dim3(64), dim3(256), 0, stream, labels, ws);
  hipLaunchKernelGGL(k_up_top, dim3(1), dim3(256), 0, stream, labels, ws);
  hipLaunchKernelGGL(k_down_top, dim3(1), dim3(256), 0, stream, labels, ws);
  hipLaunchKernelGGL(k_down_sub, dim3(64), dim3(256), 0, stream, labels, ws);
  hipLaunchKernelGGL(k_final, dim3(1), dim3(64), 0, stream, ws, out);
}